// Round 12
// baseline (49.456 us; speedup 1.0000x reference)
//
#include <hip/hip_runtime.h>
#include <math.h>

// HPSS fused: fp16 LDS *storage*, fp32 *math*, RW=16, register-fed slides.
// S (2,1,1025,2048) fp32. harm = median_31 along T (zero pad), perc = along F.
// outH = S*h^2/(h^2+p^2), outP = S*p^2/(h^2+p^2)   (softmask Z cancels).
//
// Evidence so far: VALUBusy sticky ~47% across configs; dur ~= ops/busy.
// r9 (RW=16, LDS-fed slides) and r10 (fp16 MATH: cmp+cndmask fallback) each
// broke one thing. This round: RW=16 with r11's register-fed f32 slides
// (native v_min/max/med3_f32), fp16 only as LDS container (monotone rounding
// => median commutes with the cast; r7-r10 numerics, absmax 0.0039 passed).
//   - 32(f) x 128(t) tile: H = 32 rows x 8 chunks(16), P = 128 lanes x
//     2 chunks(16); sort32 amortized /16 (24/output, was 48).
//   - LDS: tile 62x162h (stride 81 dw, odd -> conflict-free) = 20.1KB +
//     hl 32x130h = 8.3KB = 28.4KB -> 5 blocks/CU; grid 16x33x2 = 1056 <=
//     1280 resident capacity: single cohort.
// Slide = delete+insert at O(1) dependency depth:
//   D[i] = (w[i] < x_old) ? w[i] : w[i+1]; w'[i] = med3(D[i-1], x_new, D[i]).

#define DIM_T 2048
#define DIM_F 1025
#define HALF 15
#define FT 32             // output f-rows per tile
#define TT 128            // output t-cols per tile
#define RW 16             // outputs per thread along the sliding axis
#define TROWS (FT + 30)   // 62 staged rows
#define TCOLS (TT + 30)   // 158 staged cols
#define TSTRH 162         // tile row stride in halves (81 dwords, odd)
#define HSTRH 130         // hl row stride in halves
#define FEED (RW + 30)    // 46 feed values per chunk

typedef _Float16 h16;

__device__ __forceinline__ void ce(float& a, float& b) {
    const float mn = fminf(a, b);
    b = fmaxf(a, b);
    a = mn;
}

__device__ __forceinline__ void sort32(float (&a)[32]) {
#pragma unroll
    for (int p = 1; p < 32; p <<= 1) {
#pragma unroll
        for (int k = p; k >= 1; k >>= 1) {
#pragma unroll
            for (int j = k & (p - 1); j + k < 32; j += 2 * k) {
#pragma unroll
                for (int i = 0; i < k; ++i) {
                    if (i + j + k < 32) {
                        if ((i + j) / (2 * p) == (i + j + k) / (2 * p)) {
                            ce(a[i + j], a[i + j + k]);
                        }
                    }
                }
            }
        }
    }
}

// sorted-window slide: remove x_old (present in w[0..30]), insert x_new.
// w[31] must be +INF and is preserved. 31 indep (cmp+sel) + 31 indep med3.
__device__ __forceinline__ void slide(float (&w)[32], float x_old, float x_new) {
    float dprev = (w[0] < x_old) ? w[0] : w[1];
    float rprev = fminf(x_new, dprev);
#pragma unroll
    for (int i = 1; i < 31; ++i) {
        const float di = (w[i] < x_old) ? w[i] : w[i + 1];
        const float ri = __builtin_amdgcn_fmed3f(dprev, x_new, di);
        w[i - 1] = rprev;
        dprev = di;
        rprev = ri;
    }
    w[30] = rprev;
}

__global__ __launch_bounds__(256, 5) void hpss_fused(const float* __restrict__ S,
                                                     float* __restrict__ outH,
                                                     float* __restrict__ outP) {
    __shared__ h16 tile[TROWS * TSTRH];  // 20088 B
    __shared__ h16 hl[FT * HSTRH];       //  8320 B

    const int tid = threadIdx.x;
    const int t0  = blockIdx.x * TT;
    const int f0  = blockIdx.y * FT;
    const int b   = blockIdx.z;
    const float* __restrict__ Sb = S + (size_t)b * DIM_F * DIM_T;

    // ---- stage 62x158 tile as fp16 container, coalesced in t ----
    const bool interior = (blockIdx.x != 0) & (blockIdx.x != gridDim.x - 1) &
                          (f0 >= HALF) & (f0 + FT + HALF <= DIM_F);
    if (interior) {
#pragma unroll
        for (int it = 0; it < (TROWS * TCOLS + 255) / 256; ++it) {  // 39 iters
            const int li = it * 256 + tid;
            if (li < TROWS * TCOLS) {
                const int row = li / TCOLS;
                const int pos = li - row * TCOLS;
                tile[row * TSTRH + pos] =
                    (h16)Sb[(size_t)(f0 - HALF + row) * DIM_T + (t0 - HALF + pos)];
            }
        }
    } else {
#pragma unroll
        for (int it = 0; it < (TROWS * TCOLS + 255) / 256; ++it) {
            const int li = it * 256 + tid;
            if (li < TROWS * TCOLS) {
                const int row = li / TCOLS;
                const int pos = li - row * TCOLS;
                const int f = f0 - HALF + row;
                const int t = t0 - HALF + pos;
                float v = 0.0f;
                if ((unsigned)f < (unsigned)DIM_F && (unsigned)t < (unsigned)DIM_T)
                    v = Sb[(size_t)f * DIM_T + t];
                tile[row * TSTRH + pos] = (h16)v;
            }
        }
    }
    __syncthreads();

    // ---- phase H: harmonic medians (slide along t) -> hl[f][t] ----
    {
        const int fl = tid & 31;          // output f row 0..31
        const int tb = (tid >> 5) * RW;   // t chunk base 0..112
        const h16* lr = tile + (fl + HALF) * TSTRH + tb;

        // feed strip: contiguous fp16, one cvt each into f32 registers
        float r[FEED];
#pragma unroll
        for (int d = 0; d < FEED; ++d) r[d] = (float)lr[d];

        float w[32];
        w[31] = INFINITY;
#pragma unroll
        for (int d = 0; d < 31; ++d) w[d] = r[d];
        sort32(w);
#pragma unroll
        for (int s = 0; s < RW; ++s) {
            hl[fl * HSTRH + tb + s] = (h16)w[15];
            if (s < RW - 1) slide(w, r[s], r[s + 31]);   // pure-register slide
        }
    }
    __syncthreads();

    // ---- phase P: percussive medians (slide along f) + combine + store ----
    {
        const int lane = tid & 127;        // t within tile 0..127
        const int fb   = (tid >> 7) * RW;  // f chunk base 0 or 16
        const int t    = t0 + lane;

        // feed strip: 46 independent strided fp16 reads -> f32 regs
        float r[FEED];
#pragma unroll
        for (int d = 0; d < FEED; ++d)
            r[d] = (float)tile[(fb + d) * TSTRH + HALF + lane];
        // harm values for this chunk (fp16, cvt at use)
        h16 hp[RW];
#pragma unroll
        for (int s = 0; s < RW; ++s) hp[s] = hl[(fb + s) * HSTRH + lane];

        float w[32];
        w[31] = INFINITY;
#pragma unroll
        for (int d = 0; d < 31; ++d) w[d] = r[d];
        sort32(w);
#pragma unroll
        for (int s = 0; s < RW; ++s) {
            const int f = f0 + fb + s;
            if (f < DIM_F) {
                const float perc = w[15];
                const float harm = (float)hp[s];
                const float sv   = r[s + 15];   // center element, free
                const float h2 = harm * harm;
                const float p2 = perc * perc;
                const float inv = __builtin_amdgcn_rcpf(h2 + p2);  // 0 -> INF; (sv*0)*INF=NaN matches ref 0/0
                const size_t oi = ((size_t)b * DIM_F + f) * DIM_T + t;
                outH[oi] = sv * h2 * inv;
                outP[oi] = sv * p2 * inv;
            }
            if (s < RW - 1) slide(w, r[s], r[s + 31]);   // pure-register slide
        }
    }
}

extern "C" void kernel_launch(void* const* d_in, const int* in_sizes, int n_in,
                              void* d_out, int out_size, void* d_ws, size_t ws_size,
                              hipStream_t stream) {
    const float* S = (const float*)d_in[0];
    float* outH = (float*)d_out;
    float* outP = outH + (size_t)2 * DIM_F * DIM_T;

    dim3 grid(DIM_T / TT, (DIM_F + FT - 1) / FT, 2);  // 16 x 33 x 2 = 1056
    hpss_fused<<<grid, 256, 0, stream>>>(S, outH, outP);
}

// Round 13
// 35.172 us; speedup vs baseline: 1.4061x; 1.4061x over previous
//
#include <hip/hip_runtime.h>
#include <math.h>

// HPSS fused, 2-tile pipelined blocks. S (2,1,1025,2048) fp32.
// harm = median_31 along T (zero pad), perc = median_31 along F.
// outH = S*h^2/(h^2+p^2), outP = S*p^2/(h^2+p^2)   (softmask Z cancels).
//
// Diagnosis r6-r12: VALUBusy sticky ~47% at every occupancy => co-resident
// blocks stage in lockstep (latency-bound, VALU idle) then compute in
// lockstep. Fix = INTRA-block overlap (T14 issue-early/write-late): each
// block does 2 adjacent 32(f)x64(t) tiles; tile B's global loads are issued
// right after tile A is staged and consumed ~a full compute-phase later.
//   - staging: float4 global loads (6/thread; per-vec all-in/out bounds since
//     t0 % 64 == 0), scalar LDS writes -> stride 97 stays conflict-free.
//   - core: r11's proven RW=8 register-fed f32 slides (VGPR=44, no spill).
//   - hl as fp16 container (median commutes with monotone cast; r12-proven)
//     -> LDS 24.1 + 4.2 = 28.3KB -> 5 blocks/CU; grid 1056 <= 1280 capacity.
// Slide = delete+insert, O(1) dependency depth:
//   D[i] = (w[i] < x_old) ? w[i] : w[i+1]; w'[i] = med3(D[i-1], x_new, D[i]).

#define DIM_T 2048
#define DIM_F 1025
#define HALF 15
#define FT 32            // output f-rows per tile
#define TT 64            // output t-cols per tile
#define RW 8             // outputs per thread along sliding axis
#define TROWS (FT + 30)  // 62 staged rows
#define VPR 24           // float4 vecs per row (96 cols, [t0-16, t0+80))
#define TSTR 97          // dwords; odd -> conflict-free for both phases
#define HSTRH 66         // hl stride in halves (33 dwords, odd)
#define NVEC (TROWS * VPR)   // 1488
#define FEED (RW + 30)   // 38

typedef _Float16 h16;

__device__ __forceinline__ void ce(float& a, float& b) {
    const float mn = fminf(a, b);
    b = fmaxf(a, b);
    a = mn;
}

__device__ __forceinline__ void sort32(float (&a)[32]) {
#pragma unroll
    for (int p = 1; p < 32; p <<= 1) {
#pragma unroll
        for (int k = p; k >= 1; k >>= 1) {
#pragma unroll
            for (int j = k & (p - 1); j + k < 32; j += 2 * k) {
#pragma unroll
                for (int i = 0; i < k; ++i) {
                    if (i + j + k < 32) {
                        if ((i + j) / (2 * p) == (i + j + k) / (2 * p)) {
                            ce(a[i + j], a[i + j + k]);
                        }
                    }
                }
            }
        }
    }
}

// sorted-window slide: remove x_old (present in w[0..30]), insert x_new.
// w[31] must be +INF and is preserved. 31 indep (cmp+sel) + 31 indep med3.
__device__ __forceinline__ void slide(float (&w)[32], float x_old, float x_new) {
    float dprev = (w[0] < x_old) ? w[0] : w[1];
    float rprev = fminf(x_new, dprev);
#pragma unroll
    for (int i = 1; i < 31; ++i) {
        const float di = (w[i] < x_old) ? w[i] : w[i + 1];
        const float ri = __builtin_amdgcn_fmed3f(dprev, x_new, di);
        w[i - 1] = rprev;
        dprev = di;
        rprev = ri;
    }
    w[30] = rprev;
}

// load one staging vector for tile at t0x (vec index li = it*256+tid)
__device__ __forceinline__ float4 load_vec(const float* __restrict__ Sb,
                                           int f0, int t0x, int li) {
    float4 v = make_float4(0.f, 0.f, 0.f, 0.f);
    if (li < NVEC) {
        const int row = li / VPR;
        const int pos = li - row * VPR;
        const int f  = f0 - HALF + row;
        const int tg = t0x - 16 + pos * 4;
        if ((unsigned)f < (unsigned)DIM_F && (unsigned)tg <= (unsigned)(DIM_T - 4))
            v = *(const float4*)&Sb[(size_t)f * DIM_T + tg];
    }
    return v;
}

__device__ __forceinline__ void write_vec(float* __restrict__ tile, int li, float4 v) {
    if (li < NVEC) {
        const int row = li / VPR;
        const int pos = li - row * VPR;
        float* p = &tile[row * TSTR + pos * 4];
        p[0] = v.x; p[1] = v.y; p[2] = v.z; p[3] = v.w;
    }
}

__device__ __forceinline__ void compute_tile(const float* __restrict__ tile,
                                             h16* __restrict__ hl,
                                             float* __restrict__ outH,
                                             float* __restrict__ outP,
                                             int tid, int f0, int b, int t0x) {
    // ---- phase H: harmonic medians (slide along t) -> hl[f][t] ----
    {
        const int fl = tid & 31;          // output f row 0..31
        const int tb = (tid >> 5) * RW;   // t chunk base 0..56
        const float* lr = tile + (fl + HALF) * TSTR + tb + 1;  // col of t0x+tb-15

        float r[FEED];
#pragma unroll
        for (int d = 0; d < FEED; ++d) r[d] = lr[d];

        float w[32];
        w[31] = INFINITY;
#pragma unroll
        for (int d = 0; d < 31; ++d) w[d] = r[d];
        sort32(w);
#pragma unroll
        for (int s = 0; s < RW; ++s) {
            hl[fl * HSTRH + tb + s] = (h16)w[15];
            if (s < RW - 1) slide(w, r[s], r[s + 31]);
        }
    }
    __syncthreads();
    // ---- phase P: percussive medians (slide along f) + combine + store ----
    {
        const int lane = tid & 63;        // t within tile
        const int fb   = (tid >> 6) * RW; // f chunk base 0,8,16,24
        const int t    = t0x + lane;

        float r[FEED];
#pragma unroll
        for (int d = 0; d < FEED; ++d) r[d] = tile[(fb + d) * TSTR + 16 + lane];
        h16 hp[RW];
#pragma unroll
        for (int s = 0; s < RW; ++s) hp[s] = hl[(fb + s) * HSTRH + lane];

        float w[32];
        w[31] = INFINITY;
#pragma unroll
        for (int d = 0; d < 31; ++d) w[d] = r[d];
        sort32(w);
#pragma unroll
        for (int s = 0; s < RW; ++s) {
            const int f = f0 + fb + s;
            if (f < DIM_F) {
                const float perc = w[15];
                const float harm = (float)hp[s];
                const float sv   = r[s + 15];   // center element, free
                const float h2 = harm * harm;
                const float p2 = perc * perc;
                const float inv = __builtin_amdgcn_rcpf(h2 + p2);  // 0 -> INF; (sv*0)*INF=NaN matches ref 0/0
                const size_t oi = ((size_t)b * DIM_F + f) * DIM_T + t;
                outH[oi] = sv * h2 * inv;
                outP[oi] = sv * p2 * inv;
            }
            if (s < RW - 1) slide(w, r[s], r[s + 31]);
        }
    }
}

__global__ __launch_bounds__(256, 4) void hpss_fused(const float* __restrict__ S,
                                                     float* __restrict__ outH,
                                                     float* __restrict__ outP) {
    __shared__ float tile[TROWS * TSTR];  // 24056 B
    __shared__ h16 hl[FT * HSTRH];        //  4224 B

    const int tid = threadIdx.x;
    const int t0A = blockIdx.x * (2 * TT);      // tile A
    const int t0B = t0A + TT;                   // tile B
    const int f0  = blockIdx.y * FT;
    const int b   = blockIdx.z;
    const float* __restrict__ Sb = S + (size_t)b * DIM_F * DIM_T;

    // stage tile A directly
#pragma unroll
    for (int it = 0; it < 6; ++it)
        write_vec(tile, it * 256 + tid, load_vec(Sb, f0, t0A, it * 256 + tid));

    // issue tile B loads NOW; consumed a full compute-phase later (T14)
    float4 bv[6];
#pragma unroll
    for (int it = 0; it < 6; ++it) bv[it] = load_vec(Sb, f0, t0B, it * 256 + tid);

    __syncthreads();
    compute_tile(tile, hl, outH, outP, tid, f0, b, t0A);
    __syncthreads();                    // tile-A reads complete

#pragma unroll
    for (int it = 0; it < 6; ++it) write_vec(tile, it * 256 + tid, bv[it]);
    __syncthreads();
    compute_tile(tile, hl, outH, outP, tid, f0, b, t0B);
}

extern "C" void kernel_launch(void* const* d_in, const int* in_sizes, int n_in,
                              void* d_out, int out_size, void* d_ws, size_t ws_size,
                              hipStream_t stream) {
    const float* S = (const float*)d_in[0];
    float* outH = (float*)d_out;
    float* outP = outH + (size_t)2 * DIM_F * DIM_T;

    dim3 grid(DIM_T / (2 * TT), (DIM_F + FT - 1) / FT, 2);  // 16 x 33 x 2 = 1056
    hpss_fused<<<grid, 256, 0, stream>>>(S, outH, outP);
}